// Round 3
// baseline (1637.955 us; speedup 1.0000x reference)
//
#include <hip/hip_runtime.h>
#include <hip/hip_bf16.h>
#include <math.h>

// Problem constants
#define Bsz 8
#define Lseq 2048
#define ENC_IN 21
#define C_OUT 21
#define D_MODEL 512
#define D_INNER 1024
#define D_STATE 16
#define D_CONV 4
#define DT_RANK 32
#define MARK_DIM 4
#define PRED_LEN 96
#define L_TAIL (Lseq - PRED_LEN)   // 1952
#define K_EMB 80                   // 63 conv taps + 4 mark + 13 zero-pad

// ---------------------------------------------------------------------------
// 1) Instance-norm stats: mean/std over time per (b, c)
// ---------------------------------------------------------------------------
__global__ void stats_kernel(const float* __restrict__ x_enc,
                             float* __restrict__ mean, float* __restrict__ stdv) {
    int bc = blockIdx.x;               // 0..167
    int b = bc / ENC_IN, c = bc % ENC_IN;
    __shared__ float red[256];
    int t = threadIdx.x;
    float s = 0.f;
    for (int l = t; l < Lseq; l += 256)
        s += x_enc[((size_t)b * Lseq + l) * ENC_IN + c];
    red[t] = s; __syncthreads();
    for (int off = 128; off > 0; off >>= 1) {
        if (t < off) red[t] += red[t + off];
        __syncthreads();
    }
    float m = red[0] / (float)Lseq;
    __syncthreads();
    float v = 0.f;
    for (int l = t; l < Lseq; l += 256) {
        float d = x_enc[((size_t)b * Lseq + l) * ENC_IN + c] - m;
        v += d * d;
    }
    red[t] = v; __syncthreads();
    for (int off = 128; off > 0; off >>= 1) {
        if (t < off) red[t] += red[t + off];
        __syncthreads();
    }
    if (t == 0) {
        mean[bc] = m;
        stdv[bc] = sqrtf(red[0] / (float)Lseq + 1e-5f);
    }
}

// ---------------------------------------------------------------------------
// 2) Fuse head_w @ out_proj_w -> W (21 x 1024)
// ---------------------------------------------------------------------------
__global__ void fuse_w_kernel(const float* __restrict__ head_w,
                              const float* __restrict__ out_proj_w,
                              float* __restrict__ W) {
    int idx = blockIdx.x * 256 + threadIdx.x;
    if (idx >= C_OUT * D_INNER) return;
    int c = idx / D_INNER, d = idx % D_INNER;
    float s = 0.f;
    for (int k = 0; k < D_MODEL; ++k)
        s += head_w[c * D_MODEL + k] * out_proj_w[(size_t)k * D_INNER + d];
    W[idx] = s;
}

// ---------------------------------------------------------------------------
// 3a) PE table: pe[l][d], sin on even d, cos on odd d
// ---------------------------------------------------------------------------
__global__ void pe_kernel(float* __restrict__ pe) {
    int idx = blockIdx.x * 256 + threadIdx.x;        // 2048*256 (l, i) pairs
    int l = idx >> 8, i = idx & 255;
    float div = expf((float)(2 * i) * (-9.210340371976184f / (float)D_MODEL));
    float ang = (float)l * div;
    pe[(size_t)l * D_MODEL + 2 * i]     = sinf(ang);
    pe[(size_t)l * D_MODEL + 2 * i + 1] = cosf(ang);
}

// ---------------------------------------------------------------------------
// 3b) Pack embedding weights TRANSPOSED: WembT[k][d], k<63: conv tap, 63..66 mark
// ---------------------------------------------------------------------------
__global__ void prep_wT_kernel(const float* __restrict__ conv_w,
                               const float* __restrict__ temp_w,
                               float* __restrict__ WembT) {
    int idx = blockIdx.x * 256 + threadIdx.x;        // 80*512 exact
    int k = idx / D_MODEL, d = idx % D_MODEL;
    float v = 0.f;
    if (k < 3 * ENC_IN) {
        int kk = k / ENC_IN, c = k % ENC_IN;
        v = conv_w[((size_t)d * ENC_IN + c) * 3 + kk];
    } else if (k < 3 * ENC_IN + MARK_DIM) {
        v = temp_w[d * MARK_DIM + (k - 3 * ENC_IN)];
    }
    WembT[idx] = v;
}

// ---------------------------------------------------------------------------
// 3c) Build xin[bl][k]: normalized circular taps + mark features, zero pad
// ---------------------------------------------------------------------------
__global__ void prep_x_kernel(const float* __restrict__ x_enc,
                              const float* __restrict__ x_mark,
                              const float* __restrict__ mean,
                              const float* __restrict__ stdv,
                              float* __restrict__ xin) {
    int idx = blockIdx.x * 256 + threadIdx.x;        // 16384*80 exact
    int bl = idx / K_EMB, k = idx % K_EMB;
    int b = bl >> 11, l = bl & (Lseq - 1);
    float v = 0.f;
    if (k < 3 * ENC_IN) {
        int kk = k / ENC_IN, c = k % ENC_IN;
        int ll = (l + kk - 1 + Lseq) & (Lseq - 1);
        v = (x_enc[((size_t)b * Lseq + ll) * ENC_IN + c] - mean[b * ENC_IN + c])
            / stdv[b * ENC_IN + c];
    } else if (k < 3 * ENC_IN + MARK_DIM) {
        v = x_mark[((size_t)b * Lseq + l) * MARK_DIM + (k - 3 * ENC_IN)];
    }
    xin[idx] = v;
}

// ---------------------------------------------------------------------------
// 3d) Wcomb[j][k] = sum_d in_proj_w[j][d] * WembT[k][d]   (2048 x 80)
// ---------------------------------------------------------------------------
__global__ void wcomb_kernel(const float* __restrict__ in_proj_w,
                             const float* __restrict__ WembT,
                             float* __restrict__ Wcomb) {
    int idx = blockIdx.x * 256 + threadIdx.x;        // 2048*80 exact
    int j = idx / K_EMB, k = idx % K_EMB;
    const float* a = in_proj_w + (size_t)j * D_MODEL;
    const float* b = WembT + (size_t)k * D_MODEL;
    float s = 0.f;
    for (int d = 0; d < D_MODEL; d += 4) {
        float4 av = *(const float4*)(a + d);
        float4 bv = *(const float4*)(b + d);
        s += av.x * bv.x + av.y * bv.y + av.z * bv.z + av.w * bv.w;
    }
    Wcomb[idx] = s;
}

// ---------------------------------------------------------------------------
// 3e) PEpZ[lz][j] = pe[1952+lz][:] . in_proj_w[1024+j][:]   (96 x 1024)
// ---------------------------------------------------------------------------
__global__ void pepz_kernel(const float* __restrict__ pe,
                            const float* __restrict__ in_proj_w,
                            float* __restrict__ PEpZ) {
    __shared__ float per[D_MODEL];
    int lz = blockIdx.x;                  // 0..95
    int t = threadIdx.x;
    per[t] = pe[(size_t)(L_TAIL + lz) * D_MODEL + t];
    per[t + 256] = pe[(size_t)(L_TAIL + lz) * D_MODEL + t + 256];
    __syncthreads();
    for (int q = 0; q < 4; ++q) {
        int j = q * 256 + t;
        const float* w = in_proj_w + (size_t)(D_INNER + j) * D_MODEL;
        float s = 0.f;
        for (int d = 0; d < D_MODEL; d += 4) {
            float4 wv = *(const float4*)(w + d);
            s += per[d] * wv.x + per[d + 1] * wv.y + per[d + 2] * wv.z + per[d + 3] * wv.w;
        }
        PEpZ[(size_t)lz * D_INNER + j] = s;
    }
}

// ---------------------------------------------------------------------------
// 4) Generic fp32 tiled GEMM, C[M,N] = A[M,K] @ B[N,K]^T  (both row-major)
//    BM=BN=64, BK=16, 256 threads, 4x4 per thread.
//    EPI 0: plain store
//    EPI 4: add bias table indexed [(row & 2047)*N + col]   (PEp add)
//    EPI 6: A-rows remapped to last-96 slice; add bias[(row%96)*N + col] (PEpZ)
// ---------------------------------------------------------------------------
template <int EPI>
__launch_bounds__(256)
__global__ void gemm_nt(const float* __restrict__ A, const float* __restrict__ B,
                        float* __restrict__ C0, const float* __restrict__ bias,
                        int M, int N, int K, int lda, int ldb) {
    __shared__ float As[16][65];
    __shared__ float Bs[16][65];
    int bm = blockIdx.y, bn = blockIdx.x;
    int t = threadIdx.x;
    int tx = t & 15, ty = t >> 4;
    float acc[4][4] = {};
    int arow = bm * 64, bcol = bn * 64;
    int lr = t >> 2;          // 0..63
    int lk = (t & 3) * 4;     // 0,4,8,12

    size_t aRow;
    {
        int r = arow + lr;
        if (EPI == 6) {
            int rb = r / PRED_LEN;
            int rl = r - rb * PRED_LEN;
            aRow = (size_t)rb * Lseq + L_TAIL + rl;
        } else {
            aRow = (size_t)r;
        }
    }
    size_t bRow = (size_t)(bcol + lr);

    for (int k0 = 0; k0 < K; k0 += 16) {
        float4 av = *(const float4*)(A + aRow * lda + k0 + lk);
        float4 bv = *(const float4*)(B + bRow * ldb + k0 + lk);
        As[lk + 0][lr] = av.x; As[lk + 1][lr] = av.y;
        As[lk + 2][lr] = av.z; As[lk + 3][lr] = av.w;
        Bs[lk + 0][lr] = bv.x; Bs[lk + 1][lr] = bv.y;
        Bs[lk + 2][lr] = bv.z; Bs[lk + 3][lr] = bv.w;
        __syncthreads();
        #pragma unroll
        for (int kk = 0; kk < 16; ++kk) {
            float a[4], bq[4];
            #pragma unroll
            for (int i = 0; i < 4; ++i) a[i] = As[kk][ty * 4 + i];
            #pragma unroll
            for (int j = 0; j < 4; ++j) bq[j] = Bs[kk][tx * 4 + j];
            #pragma unroll
            for (int i = 0; i < 4; ++i)
                #pragma unroll
                for (int j = 0; j < 4; ++j)
                    acc[i][j] += a[i] * bq[j];
        }
        __syncthreads();
    }

    #pragma unroll
    for (int i = 0; i < 4; ++i) {
        int row = arow + ty * 4 + i;
        #pragma unroll
        for (int j = 0; j < 4; ++j) {
            int col = bcol + tx * 4 + j;
            float v = acc[i][j];
            if (EPI == 4) {
                v += bias[(size_t)(row & (Lseq - 1)) * N + col];
            }
            if (EPI == 6) {
                int rl = row - (row / PRED_LEN) * PRED_LEN;
                v += bias[(size_t)rl * N + col];
            }
            C0[(size_t)row * N + col] = v;
        }
    }
}

// ---------------------------------------------------------------------------
// 5) Depthwise causal conv1d (k=4) + SiLU
// ---------------------------------------------------------------------------
__global__ void dwconv_kernel(const float* __restrict__ xs_raw,
                              const float* __restrict__ w,
                              const float* __restrict__ bias,
                              float* __restrict__ out) {
    size_t idx = (size_t)blockIdx.x * 256 + threadIdx.x;
    if (idx >= (size_t)Bsz * Lseq * D_INNER) return;
    int d = idx & (D_INNER - 1);
    size_t bl = idx >> 10;
    int l = (int)(bl & (Lseq - 1));
    float acc = bias[d];
    #pragma unroll
    for (int k = 0; k < D_CONV; ++k) {
        int ll = l - (D_CONV - 1) + k;
        if (ll >= 0)
            acc += xs_raw[(bl - (D_CONV - 1) + k) * D_INNER + d] * w[d * D_CONV + k];
    }
    out[idx] = acc / (1.f + __expf(-acc));   // SiLU
}

// ---------------------------------------------------------------------------
// 6) Selective scan with FUSED dt_proj + softplus.
//    Lane = one (d, n) state; 16 lanes per d-channel share the rank-32 dt dot
//    (2 MACs/lane + xor-butterfly allreduce). Emits y only for l >= L_TAIL,
//    fused with +u*D and *silu(z).
// ---------------------------------------------------------------------------
__launch_bounds__(256)
__global__ void scan_kernel(const float* __restrict__ u,
                            const float* __restrict__ xdbl,
                            const float* __restrict__ A_log,
                            const float* __restrict__ Dp,
                            const float* __restrict__ dt_w,
                            const float* __restrict__ dt_b,
                            const float* __restrict__ z96,
                            float* __restrict__ y96) {
    int b = blockIdx.x >> 6;
    int dg = blockIdx.x & 63;
    int t = threadIdx.x;
    int d = dg * 16 + (t >> 4);
    int n = t & 15;
    float A = -__expf(A_log[d * D_STATE + n]);
    float Dd = Dp[d];
    float w0 = dt_w[d * DT_RANK + 2 * n];
    float w1 = dt_w[d * DT_RANK + 2 * n + 1];
    float bias = dt_b[d];
    float h = 0.f;
    const size_t rowU = (size_t)b * Lseq * D_INNER + d;
    const size_t rowX = (size_t)b * Lseq * 64;

    for (int l0 = 0; l0 < Lseq; l0 += 4) {
        float2 x2[4];
        float uu[4], Bv[4], Cv[4], dl[4];
        #pragma unroll
        for (int j = 0; j < 4; ++j) {
            size_t xo = rowX + (size_t)(l0 + j) * 64;
            x2[j] = *(const float2*)(xdbl + xo + 2 * n);
            Bv[j] = xdbl[xo + DT_RANK + n];
            Cv[j] = xdbl[xo + DT_RANK + D_STATE + n];
            uu[j] = u[rowU + (size_t)(l0 + j) * D_INNER];
        }
        // rank-32 dt dot, shared across the 16 lanes of this d-channel
        #pragma unroll
        for (int j = 0; j < 4; ++j) {
            float p = w0 * x2[j].x + w1 * x2[j].y;
            #pragma unroll
            for (int m = 8; m >= 1; m >>= 1) p += __shfl_xor(p, m, 16);
            float s = p + bias;
            dl[j] = (s > 20.f) ? s : log1pf(__expf(s));   // softplus
        }
        #pragma unroll
        for (int j = 0; j < 4; ++j) {
            int l = l0 + j;
            h = __expf(dl[j] * A) * h + (dl[j] * uu[j]) * Bv[j];
            if (l >= L_TAIL) {
                float y = h * Cv[j];
                #pragma unroll
                for (int m = 8; m >= 1; m >>= 1) y += __shfl_xor(y, m, 16);
                if (n == 0) {
                    size_t o = ((size_t)b * PRED_LEN + (l - L_TAIL)) * D_INNER + d;
                    float z = z96[o];
                    y96[o] = (y + uu[j] * Dd) * (z / (1.f + __expf(-z)));
                }
            }
        }
    }
}

// ---------------------------------------------------------------------------
// 7) Final head: out[b,t,c] = (y96[b,t,:] . W[c,:]) * std[b,c] + mean[b,c]
// ---------------------------------------------------------------------------
__global__ void head_kernel(const float* __restrict__ y96,
                            const float* __restrict__ W,
                            const float* __restrict__ mean,
                            const float* __restrict__ stdv,
                            float* __restrict__ out) {
    int idx = blockIdx.x;                 // 8*96*21
    int c = idx % C_OUT;
    int bt = idx / C_OUT;
    int b = bt / PRED_LEN;
    int lane = threadIdx.x;
    const float* yrow = y96 + (size_t)bt * D_INNER;
    const float* wrow = W + (size_t)c * D_INNER;
    float s = 0.f;
    for (int d = lane; d < D_INNER; d += 64) s += yrow[d] * wrow[d];
    #pragma unroll
    for (int m = 32; m >= 1; m >>= 1) s += __shfl_xor(s, m, 64);
    if (lane == 0)
        out[(size_t)bt * C_OUT + c] = s * stdv[b * C_OUT + c] + mean[b * C_OUT + c];
}

// ---------------------------------------------------------------------------
extern "C" void kernel_launch(void* const* d_in, const int* in_sizes, int n_in,
                              void* d_out, int out_size, void* d_ws, size_t ws_size,
                              hipStream_t stream) {
    const float* x_enc     = (const float*)d_in[0];
    const float* x_mark    = (const float*)d_in[1];
    const float* conv_w    = (const float*)d_in[4];
    const float* temp_w    = (const float*)d_in[5];
    const float* in_proj_w = (const float*)d_in[6];
    const float* conv1d_w  = (const float*)d_in[7];
    const float* conv1d_b  = (const float*)d_in[8];
    const float* x_proj_w  = (const float*)d_in[9];
    const float* dt_proj_w = (const float*)d_in[10];
    const float* dt_proj_b = (const float*)d_in[11];
    const float* A_log     = (const float*)d_in[12];
    const float* Dp        = (const float*)d_in[13];
    const float* out_proj_w= (const float*)d_in[14];
    const float* head_w    = (const float*)d_in[15];
    float* out = (float*)d_out;
    float* ws = (float*)d_ws;

    // workspace layout (floats) — NO aliasing, every buffer exclusive.
    // Total ~41.0M floats = 164 MB.
    size_t off = 0;
    float* mean    = ws + off; off += 256;
    float* stdv    = ws + off; off += 256;
    float* W       = ws + off; off += (size_t)C_OUT * D_INNER;           // 21504
    float* WembT   = ws + off; off += (size_t)K_EMB * D_MODEL;           // 40960
    float* Wcomb   = ws + off; off += (size_t)2 * D_INNER * K_EMB;       // 163840
    float* PEp     = ws + off; off += (size_t)Lseq * D_INNER;            // 2.10M
    float* PEpZ    = ws + off; off += (size_t)PRED_LEN * D_INNER;        // 98304
    float* pe      = ws + off; off += (size_t)Lseq * D_MODEL;            // 1.05M
    float* xin     = ws + off; off += (size_t)Bsz * Lseq * K_EMB;        // 1.31M
    float* xs_raw  = ws + off; off += (size_t)Bsz * Lseq * D_INNER;      // 16.8M
    float* z96     = ws + off; off += (size_t)Bsz * PRED_LEN * D_INNER;  // 0.79M
    float* xs_conv = ws + off; off += (size_t)Bsz * Lseq * D_INNER;      // 16.8M
    float* xdbl    = ws + off; off += (size_t)Bsz * Lseq * 64;           // 1.05M
    float* y96     = ws + off; off += (size_t)Bsz * PRED_LEN * D_INNER;  // 0.79M

    const int M = Bsz * Lseq;   // 16384

    // 1) instance-norm stats
    stats_kernel<<<Bsz * ENC_IN, 256, 0, stream>>>(x_enc, mean, stdv);
    // 2) fused output weight
    fuse_w_kernel<<<(C_OUT * D_INNER + 255) / 256, 256, 0, stream>>>(head_w, out_proj_w, W);
    // 3) precomputations for the embed*in_proj fusion
    pe_kernel<<<(Lseq * (D_MODEL / 2)) / 256, 256, 0, stream>>>(pe);
    prep_wT_kernel<<<(K_EMB * D_MODEL) / 256, 256, 0, stream>>>(conv_w, temp_w, WembT);
    prep_x_kernel<<<(M * K_EMB) / 256, 256, 0, stream>>>(x_enc, x_mark, mean, stdv, xin);
    wcomb_kernel<<<(2 * D_INNER * K_EMB) / 256, 256, 0, stream>>>(in_proj_w, WembT, Wcomb);
    // PEp = pe (2048x512) @ in_proj_xs (1024x512)^T
    gemm_nt<0><<<dim3(D_INNER / 64, Lseq / 64), 256, 0, stream>>>(
        pe, in_proj_w, PEp, nullptr, Lseq, D_INNER, D_MODEL, D_MODEL, D_MODEL);
    pepz_kernel<<<PRED_LEN, 256, 0, stream>>>(pe, in_proj_w, PEpZ);
    // 4a) fused xs half: xs_raw = xin @ Wcomb_xs^T + PEp[l]   (16384x1024, K=80)
    gemm_nt<4><<<dim3(D_INNER / 64, M / 64), 256, 0, stream>>>(
        xin, Wcomb, xs_raw, PEp, M, D_INNER, K_EMB, K_EMB, K_EMB);
    // 4b) fused z half, last 96 rows per batch: z96 = xin[tail] @ Wcomb_z^T + PEpZ
    gemm_nt<6><<<dim3(D_INNER / 64, (Bsz * PRED_LEN) / 64), 256, 0, stream>>>(
        xin, Wcomb + (size_t)D_INNER * K_EMB, z96, PEpZ,
        Bsz * PRED_LEN, D_INNER, K_EMB, K_EMB, K_EMB);
    // 5) depthwise causal conv + SiLU
    dwconv_kernel<<<(M * D_INNER) / 256, 256, 0, stream>>>(xs_raw, conv1d_w, conv1d_b, xs_conv);
    // 6) x_proj: (16384 x 1024) @ (64 x 1024)^T
    gemm_nt<0><<<dim3(1, M / 64), 256, 0, stream>>>(
        xs_conv, x_proj_w, xdbl, nullptr, M, 64, D_INNER, D_INNER, D_INNER);
    // 7) selective scan (+ fused dt_proj/softplus + gate)
    scan_kernel<<<Bsz * 64, 256, 0, stream>>>(xs_conv, xdbl, A_log, Dp,
                                              dt_proj_w, dt_proj_b, z96, y96);
    // 8) head + de-normalize
    head_kernel<<<Bsz * PRED_LEN * C_OUT, 64, 0, stream>>>(y96, W, mean, stdv, out);
}

// Round 4
// 678.186 us; speedup vs baseline: 2.4152x; 2.4152x over previous
//
#include <hip/hip_runtime.h>
#include <hip/hip_bf16.h>
#include <math.h>

// Problem constants
#define Bsz 8
#define Lseq 2048
#define ENC_IN 21
#define C_OUT 21
#define D_MODEL 512
#define D_INNER 1024
#define D_STATE 16
#define D_CONV 4
#define DT_RANK 32
#define MARK_DIM 4
#define PRED_LEN 96
#define L_TAIL (Lseq - PRED_LEN)   // 1952
#define K_EMB 80                   // 63 conv taps + 4 mark + 13 zero-pad
#define CHUNK 128
#define NCHUNK_A 15                // chunks 0..14 in pass A; chunk 15 in pass B

#define PE_C0 (-9.210340371976184f / (float)D_MODEL)   // -ln(10000)/d_model

// ---------------------------------------------------------------------------
// 1) Instance-norm stats: mean/std over time per (b, c)
// ---------------------------------------------------------------------------
__global__ void stats_kernel(const float* __restrict__ x_enc,
                             float* __restrict__ mean, float* __restrict__ stdv) {
    int bc = blockIdx.x;               // 0..167
    int b = bc / ENC_IN, c = bc % ENC_IN;
    __shared__ float red[256];
    int t = threadIdx.x;
    float s = 0.f;
    for (int l = t; l < Lseq; l += 256)
        s += x_enc[((size_t)b * Lseq + l) * ENC_IN + c];
    red[t] = s; __syncthreads();
    for (int off = 128; off > 0; off >>= 1) {
        if (t < off) red[t] += red[t + off];
        __syncthreads();
    }
    float m = red[0] / (float)Lseq;
    __syncthreads();
    float v = 0.f;
    for (int l = t; l < Lseq; l += 256) {
        float d = x_enc[((size_t)b * Lseq + l) * ENC_IN + c] - m;
        v += d * d;
    }
    red[t] = v; __syncthreads();
    for (int off = 128; off > 0; off >>= 1) {
        if (t < off) red[t] += red[t + off];
        __syncthreads();
    }
    if (t == 0) {
        mean[bc] = m;
        stdv[bc] = sqrtf(red[0] / (float)Lseq + 1e-5f);
    }
}

// ---------------------------------------------------------------------------
// 2) Fuse head_w @ out_proj_w -> W (21 x 1024)
// ---------------------------------------------------------------------------
__global__ void fuse_w_kernel(const float* __restrict__ head_w,
                              const float* __restrict__ out_proj_w,
                              float* __restrict__ W) {
    int idx = blockIdx.x * 256 + threadIdx.x;
    if (idx >= C_OUT * D_INNER) return;
    int c = idx / D_INNER, d = idx % D_INNER;
    float s = 0.f;
    for (int k = 0; k < D_MODEL; ++k)
        s += head_w[c * D_MODEL + k] * out_proj_w[(size_t)k * D_INNER + d];
    W[idx] = s;
}

// ---------------------------------------------------------------------------
// 3a) Pack embedding weights TRANSPOSED: WembT[k][d]
// ---------------------------------------------------------------------------
__global__ void prep_wT_kernel(const float* __restrict__ conv_w,
                               const float* __restrict__ temp_w,
                               float* __restrict__ WembT) {
    int idx = blockIdx.x * 256 + threadIdx.x;        // 80*512 exact
    int k = idx / D_MODEL, d = idx % D_MODEL;
    float v = 0.f;
    if (k < 3 * ENC_IN) {
        int kk = k / ENC_IN, c = k % ENC_IN;
        v = conv_w[((size_t)d * ENC_IN + c) * 3 + kk];
    } else if (k < 3 * ENC_IN + MARK_DIM) {
        v = temp_w[d * MARK_DIM + (k - 3 * ENC_IN)];
    }
    WembT[idx] = v;
}

// ---------------------------------------------------------------------------
// 3b) Build xin[bl][k]: normalized circular taps + mark features, zero pad
// ---------------------------------------------------------------------------
__global__ void prep_x_kernel(const float* __restrict__ x_enc,
                              const float* __restrict__ x_mark,
                              const float* __restrict__ mean,
                              const float* __restrict__ stdv,
                              float* __restrict__ xin) {
    int idx = blockIdx.x * 256 + threadIdx.x;        // 16384*80 exact
    int bl = idx / K_EMB, k = idx % K_EMB;
    int b = bl >> 11, l = bl & (Lseq - 1);
    float v = 0.f;
    if (k < 3 * ENC_IN) {
        int kk = k / ENC_IN, c = k % ENC_IN;
        int ll = (l + kk - 1 + Lseq) & (Lseq - 1);
        v = (x_enc[((size_t)b * Lseq + ll) * ENC_IN + c] - mean[b * ENC_IN + c])
            / stdv[b * ENC_IN + c];
    } else if (k < 3 * ENC_IN + MARK_DIM) {
        v = x_mark[((size_t)b * Lseq + l) * MARK_DIM + (k - 3 * ENC_IN)];
    }
    xin[idx] = v;
}

// ---------------------------------------------------------------------------
// 3c) Wcomb[j][k] = sum_d in_proj_w[j][d] * WembT[k][d]   (2048 x 80)
// ---------------------------------------------------------------------------
__global__ void wcomb_kernel(const float* __restrict__ in_proj_w,
                             const float* __restrict__ WembT,
                             float* __restrict__ Wcomb) {
    int idx = blockIdx.x * 256 + threadIdx.x;        // 2048*80 exact
    int j = idx / K_EMB, k = idx % K_EMB;
    const float* a = in_proj_w + (size_t)j * D_MODEL;
    const float* b = WembT + (size_t)k * D_MODEL;
    float s = 0.f;
    for (int d = 0; d < D_MODEL; d += 4) {
        float4 av = *(const float4*)(a + d);
        float4 bv = *(const float4*)(b + d);
        s += av.x * bv.x + av.y * bv.y + av.z * bv.z + av.w * bv.w;
    }
    Wcomb[idx] = s;
}

// ---------------------------------------------------------------------------
// 3d) PEpZ[lz][j] = pe[1952+lz][:] . in_proj_w[1024+j][:]  (96 x 1024)
//     pe row computed analytically in LDS.
// ---------------------------------------------------------------------------
__global__ void pepz_kernel(const float* __restrict__ in_proj_w,
                            float* __restrict__ PEpZ) {
    __shared__ float per[D_MODEL];
    int lz = blockIdx.x;                  // 0..95
    int t = threadIdx.x;
    {
        int l = L_TAIL + lz;
        float div = __expf((float)(2 * t) * PE_C0);
        float s, c;
        sincosf((float)l * div, &s, &c);
        per[2 * t] = s;
        per[2 * t + 1] = c;
    }
    __syncthreads();
    for (int q = 0; q < 4; ++q) {
        int j = q * 256 + t;
        const float* w = in_proj_w + (size_t)(D_INNER + j) * D_MODEL;
        float s = 0.f;
        for (int d = 0; d < D_MODEL; d += 4) {
            float4 wv = *(const float4*)(w + d);
            s += per[d] * wv.x + per[d + 1] * wv.y + per[d + 2] * wv.z + per[d + 3] * wv.w;
        }
        PEpZ[(size_t)lz * D_INNER + j] = s;
    }
}

// ---------------------------------------------------------------------------
// 4) Generic fp32 tiled GEMM, C[M,N] = A[M,K] @ B[N,K]^T  (both row-major)
//    BM=BN=64, BK=16, 256 threads, 4x4 per thread.
//    EPI 0: plain store
//    EPI 2: bias[col] + softplus
//    EPI 4: add bias table indexed [(row & 2047)*N + col]   (PEp add)
//    EPI 5: A generated analytically as the PE table (A ptr unused)
//    EPI 6: A-rows remapped to last-96 slice; add bias[(row%96)*N + col]
// ---------------------------------------------------------------------------
template <int EPI>
__launch_bounds__(256)
__global__ void gemm_nt(const float* __restrict__ A, const float* __restrict__ B,
                        float* __restrict__ C0, const float* __restrict__ bias,
                        int M, int N, int K, int lda, int ldb) {
    __shared__ float As[16][65];
    __shared__ float Bs[16][65];
    int bm = blockIdx.y, bn = blockIdx.x;
    int t = threadIdx.x;
    int tx = t & 15, ty = t >> 4;
    float acc[4][4] = {};
    int arow = bm * 64, bcol = bn * 64;
    int lr = t >> 2;          // 0..63
    int lk = (t & 3) * 4;     // 0,4,8,12

    size_t aRow;
    {
        int r = arow + lr;
        if (EPI == 6) {
            int rb = r / PRED_LEN;
            int rl = r - rb * PRED_LEN;
            aRow = (size_t)rb * Lseq + L_TAIL + rl;
        } else {
            aRow = (size_t)r;
        }
    }
    size_t bRow = (size_t)(bcol + lr);

    for (int k0 = 0; k0 < K; k0 += 16) {
        float4 av;
        if constexpr (EPI == 5) {
            // A[l][k] = (k even) ? sin(l*div(k/2)) : cos(l*div(k/2)),
            // div(i) = exp(2i * (-ln 1e4 / 512));  lk is a multiple of 4.
            int kbase = k0 + lk;
            float l = (float)(int)aRow;
            float d0 = __expf((float)kbase * PE_C0);
            float d1 = __expf((float)(kbase + 2) * PE_C0);
            sincosf(l * d0, &av.x, &av.y);
            sincosf(l * d1, &av.z, &av.w);
        } else {
            av = *(const float4*)(A + aRow * lda + k0 + lk);
        }
        float4 bv = *(const float4*)(B + bRow * ldb + k0 + lk);
        As[lk + 0][lr] = av.x; As[lk + 1][lr] = av.y;
        As[lk + 2][lr] = av.z; As[lk + 3][lr] = av.w;
        Bs[lk + 0][lr] = bv.x; Bs[lk + 1][lr] = bv.y;
        Bs[lk + 2][lr] = bv.z; Bs[lk + 3][lr] = bv.w;
        __syncthreads();
        #pragma unroll
        for (int kk = 0; kk < 16; ++kk) {
            float a[4], bq[4];
            #pragma unroll
            for (int i = 0; i < 4; ++i) a[i] = As[kk][ty * 4 + i];
            #pragma unroll
            for (int j = 0; j < 4; ++j) bq[j] = Bs[kk][tx * 4 + j];
            #pragma unroll
            for (int i = 0; i < 4; ++i)
                #pragma unroll
                for (int j = 0; j < 4; ++j)
                    acc[i][j] += a[i] * bq[j];
        }
        __syncthreads();
    }

    #pragma unroll
    for (int i = 0; i < 4; ++i) {
        int row = arow + ty * 4 + i;
        #pragma unroll
        for (int j = 0; j < 4; ++j) {
            int col = bcol + tx * 4 + j;
            float v = acc[i][j];
            if (EPI == 2) {
                v += bias[col];
                v = (v > 20.f) ? v : log1pf(__expf(v));
            }
            if (EPI == 4) {
                v += bias[(size_t)(row & (Lseq - 1)) * N + col];
            }
            if (EPI == 6) {
                int rl = row - (row / PRED_LEN) * PRED_LEN;
                v += bias[(size_t)rl * N + col];
            }
            C0[(size_t)row * N + col] = v;
        }
    }
}

// ---------------------------------------------------------------------------
// 5) Depthwise causal conv1d (k=4) + SiLU
// ---------------------------------------------------------------------------
__global__ void dwconv_kernel(const float* __restrict__ xs_raw,
                              const float* __restrict__ w,
                              const float* __restrict__ bias,
                              float* __restrict__ out) {
    size_t idx = (size_t)blockIdx.x * 256 + threadIdx.x;
    if (idx >= (size_t)Bsz * Lseq * D_INNER) return;
    int d = idx & (D_INNER - 1);
    size_t bl = idx >> 10;
    int l = (int)(bl & (Lseq - 1));
    float acc = bias[d];
    #pragma unroll
    for (int k = 0; k < D_CONV; ++k) {
        int ll = l - (D_CONV - 1) + k;
        if (ll >= 0)
            acc += xs_raw[(bl - (D_CONV - 1) + k) * D_INNER + d] * w[d * D_CONV + k];
    }
    out[idx] = acc / (1.f + __expf(-acc));   // SiLU
}

// ---------------------------------------------------------------------------
// 6a) Chunked scan, pass A: per-chunk (P, S) for chunks 0..14.
//     h_out = P*h_in + S with a_l = exp(delta*A), b_l = delta*u*B.
//     Lane = one (d,n); 16 d-channels per block; grid (512, 15).
// ---------------------------------------------------------------------------
__launch_bounds__(256)
__global__ void scanA_kernel(const float* __restrict__ delta,
                             const float* __restrict__ u,
                             const float* __restrict__ xdbl,
                             const float* __restrict__ A_log,
                             float* __restrict__ Pa,
                             float* __restrict__ Sa) {
    int b = blockIdx.x >> 6;
    int dg = blockIdx.x & 63;
    int c = blockIdx.y;                 // 0..14
    int t = threadIdx.x;
    int d = dg * 16 + (t >> 4);
    int n = t & 15;
    float A = -__expf(A_log[d * D_STATE + n]);
    float P = 1.f, S = 0.f;
    const size_t rowD = (size_t)b * Lseq * D_INNER + d;
    const size_t rowX = (size_t)b * Lseq * 64;
    const int l0b = c * CHUNK;

    for (int l0 = l0b; l0 < l0b + CHUNK; l0 += 4) {
        float dl[4], uu[4], Bv[4];
        #pragma unroll
        for (int j = 0; j < 4; ++j) {
            size_t off = rowD + (size_t)(l0 + j) * D_INNER;
            dl[j] = delta[off];
            uu[j] = u[off];
            Bv[j] = xdbl[rowX + (size_t)(l0 + j) * 64 + DT_RANK + n];
        }
        #pragma unroll
        for (int j = 0; j < 4; ++j) {
            float a = __expf(dl[j] * A);
            P *= a;
            S = a * S + (dl[j] * uu[j]) * Bv[j];
        }
    }
    size_t o = ((size_t)(b * NCHUNK_A + c) * 64 + dg) * 256 + t;
    Pa[o] = P;
    Sa[o] = S;
}

// ---------------------------------------------------------------------------
// 6b) Chunked scan, pass B: combine chunk factors, scan final chunk, emit y.
// ---------------------------------------------------------------------------
__launch_bounds__(256)
__global__ void scanB_kernel(const float* __restrict__ delta,
                             const float* __restrict__ u,
                             const float* __restrict__ xdbl,
                             const float* __restrict__ A_log,
                             const float* __restrict__ Dp,
                             const float* __restrict__ Pa,
                             const float* __restrict__ Sa,
                             const float* __restrict__ z96,
                             float* __restrict__ y96) {
    int b = blockIdx.x >> 6;
    int dg = blockIdx.x & 63;
    int t = threadIdx.x;
    int d = dg * 16 + (t >> 4);
    int n = t & 15;
    float A = -__expf(A_log[d * D_STATE + n]);
    float Dd = Dp[d];
    float h = 0.f;
    for (int c = 0; c < NCHUNK_A; ++c) {
        size_t o = ((size_t)(b * NCHUNK_A + c) * 64 + dg) * 256 + t;
        h = Pa[o] * h + Sa[o];
    }
    const size_t rowD = (size_t)b * Lseq * D_INNER + d;
    const size_t rowX = (size_t)b * Lseq * 64;

    for (int l0 = NCHUNK_A * CHUNK; l0 < Lseq; l0 += 4) {
        float dl[4], uu[4], Bv[4], Cv[4];
        #pragma unroll
        for (int j = 0; j < 4; ++j) {
            size_t off = rowD + (size_t)(l0 + j) * D_INNER;
            dl[j] = delta[off];
            uu[j] = u[off];
            Bv[j] = xdbl[rowX + (size_t)(l0 + j) * 64 + DT_RANK + n];
            Cv[j] = xdbl[rowX + (size_t)(l0 + j) * 64 + DT_RANK + D_STATE + n];
        }
        #pragma unroll
        for (int j = 0; j < 4; ++j) {
            int l = l0 + j;
            h = __expf(dl[j] * A) * h + (dl[j] * uu[j]) * Bv[j];
            if (l >= L_TAIL) {
                float y = h * Cv[j];
                #pragma unroll
                for (int m = 8; m >= 1; m >>= 1) y += __shfl_xor(y, m, 16);
                if (n == 0) {
                    size_t o = ((size_t)b * PRED_LEN + (l - L_TAIL)) * D_INNER + d;
                    float z = z96[o];
                    y96[o] = (y + uu[j] * Dd) * (z / (1.f + __expf(-z)));
                }
            }
        }
    }
}

// ---------------------------------------------------------------------------
// 7) Final head: out[b,t,c] = (y96[b,t,:] . W[c,:]) * std[b,c] + mean[b,c]
// ---------------------------------------------------------------------------
__global__ void head_kernel(const float* __restrict__ y96,
                            const float* __restrict__ W,
                            const float* __restrict__ mean,
                            const float* __restrict__ stdv,
                            float* __restrict__ out) {
    int idx = blockIdx.x;                 // 8*96*21
    int c = idx % C_OUT;
    int bt = idx / C_OUT;
    int b = bt / PRED_LEN;
    int lane = threadIdx.x;
    const float* yrow = y96 + (size_t)bt * D_INNER;
    const float* wrow = W + (size_t)c * D_INNER;
    float s = 0.f;
    for (int d = lane; d < D_INNER; d += 64) s += yrow[d] * wrow[d];
    #pragma unroll
    for (int m = 32; m >= 1; m >>= 1) s += __shfl_xor(s, m, 64);
    if (lane == 0)
        out[(size_t)bt * C_OUT + c] = s * stdv[b * C_OUT + c] + mean[b * C_OUT + c];
}

// ---------------------------------------------------------------------------
extern "C" void kernel_launch(void* const* d_in, const int* in_sizes, int n_in,
                              void* d_out, int out_size, void* d_ws, size_t ws_size,
                              hipStream_t stream) {
    const float* x_enc     = (const float*)d_in[0];
    const float* x_mark    = (const float*)d_in[1];
    const float* conv_w    = (const float*)d_in[4];
    const float* temp_w    = (const float*)d_in[5];
    const float* in_proj_w = (const float*)d_in[6];
    const float* conv1d_w  = (const float*)d_in[7];
    const float* conv1d_b  = (const float*)d_in[8];
    const float* x_proj_w  = (const float*)d_in[9];
    const float* dt_proj_w = (const float*)d_in[10];
    const float* dt_proj_b = (const float*)d_in[11];
    const float* A_log     = (const float*)d_in[12];
    const float* Dp        = (const float*)d_in[13];
    const float* out_proj_w= (const float*)d_in[14];
    const float* head_w    = (const float*)d_in[15];
    float* out = (float*)d_out;
    float* ws = (float*)d_ws;

    // workspace layout (floats) — NO aliasing. Total 60.62M floats = 242.5 MB
    // (strictly below the R1-proven 245.5 MB).
    size_t off = 0;
    float* mean    = ws + off; off += 256;
    float* stdv    = ws + off; off += 256;
    float* W       = ws + off; off += (size_t)C_OUT * D_INNER;            // 21504
    float* WembT   = ws + off; off += (size_t)K_EMB * D_MODEL;            // 40960
    float* Wcomb   = ws + off; off += (size_t)2 * D_INNER * K_EMB;        // 163840
    float* PEp     = ws + off; off += (size_t)Lseq * D_INNER;             // 2.10M
    float* PEpZ    = ws + off; off += (size_t)PRED_LEN * D_INNER;         // 98304
    float* xin     = ws + off; off += (size_t)Bsz * Lseq * K_EMB;         // 1.31M
    float* xs_raw  = ws + off; off += (size_t)Bsz * Lseq * D_INNER;       // 16.8M
    float* z96     = ws + off; off += (size_t)Bsz * PRED_LEN * D_INNER;   // 0.79M
    float* xs_conv = ws + off; off += (size_t)Bsz * Lseq * D_INNER;       // 16.8M
    float* xdbl    = ws + off; off += (size_t)Bsz * Lseq * 64;            // 1.05M
    float* delta   = ws + off; off += (size_t)Bsz * Lseq * D_INNER;       // 16.8M
    float* Pa      = ws + off; off += (size_t)Bsz * NCHUNK_A * D_INNER * D_STATE; // 1.97M
    float* Sa      = ws + off; off += (size_t)Bsz * NCHUNK_A * D_INNER * D_STATE; // 1.97M
    float* y96     = ws + off; off += (size_t)Bsz * PRED_LEN * D_INNER;   // 0.79M

    const int M = Bsz * Lseq;   // 16384

    // 1) instance-norm stats
    stats_kernel<<<Bsz * ENC_IN, 256, 0, stream>>>(x_enc, mean, stdv);
    // 2) fused output weight
    fuse_w_kernel<<<(C_OUT * D_INNER + 255) / 256, 256, 0, stream>>>(head_w, out_proj_w, W);
    // 3) precomputations for the embed*in_proj fusion
    prep_wT_kernel<<<(K_EMB * D_MODEL) / 256, 256, 0, stream>>>(conv_w, temp_w, WembT);
    prep_x_kernel<<<(M * K_EMB) / 256, 256, 0, stream>>>(x_enc, x_mark, mean, stdv, xin);
    wcomb_kernel<<<(2 * D_INNER * K_EMB) / 256, 256, 0, stream>>>(in_proj_w, WembT, Wcomb);
    // PEp = pe(analytic, 2048x512) @ in_proj_xs (1024x512)^T
    gemm_nt<5><<<dim3(D_INNER / 64, Lseq / 64), 256, 0, stream>>>(
        nullptr, in_proj_w, PEp, nullptr, Lseq, D_INNER, D_MODEL, 0, D_MODEL);
    pepz_kernel<<<PRED_LEN, 256, 0, stream>>>(in_proj_w, PEpZ);
    // 4a) fused xs half: xs_raw = xin @ Wcomb_xs^T + PEp[l]   (16384x1024, K=80)
    gemm_nt<4><<<dim3(D_INNER / 64, M / 64), 256, 0, stream>>>(
        xin, Wcomb, xs_raw, PEp, M, D_INNER, K_EMB, K_EMB, K_EMB);
    // 4b) fused z half, last 96 rows per batch: z96 = xin[tail] @ Wcomb_z^T + PEpZ
    gemm_nt<6><<<dim3(D_INNER / 64, (Bsz * PRED_LEN) / 64), 256, 0, stream>>>(
        xin, Wcomb + (size_t)D_INNER * K_EMB, z96, PEpZ,
        Bsz * PRED_LEN, D_INNER, K_EMB, K_EMB, K_EMB);
    // 5) depthwise causal conv + SiLU
    dwconv_kernel<<<(M * D_INNER) / 256, 256, 0, stream>>>(xs_raw, conv1d_w, conv1d_b, xs_conv);
    // 6) x_proj: (16384 x 1024) @ (64 x 1024)^T
    gemm_nt<0><<<dim3(1, M / 64), 256, 0, stream>>>(
        xs_conv, x_proj_w, xdbl, nullptr, M, 64, D_INNER, D_INNER, D_INNER);
    // 7) dt_proj + softplus: (16384 x 32) @ (1024 x 32)^T -> delta
    gemm_nt<2><<<dim3(D_INNER / 64, M / 64), 256, 0, stream>>>(
        xdbl, dt_proj_w, delta, dt_proj_b, M, D_INNER, DT_RANK, 64, DT_RANK);
    // 8) chunked selective scan: pass A (chunks 0..14), pass B (combine + tail)
    scanA_kernel<<<dim3(Bsz * 64, NCHUNK_A), 256, 0, stream>>>(
        delta, xs_conv, xdbl, A_log, Pa, Sa);
    scanB_kernel<<<Bsz * 64, 256, 0, stream>>>(
        delta, xs_conv, xdbl, A_log, Dp, Pa, Sa, z96, y96);
    // 9) head + de-normalize
    head_kernel<<<Bsz * PRED_LEN * C_OUT, 64, 0, stream>>>(y96, W, mean, stdv, out);
}

// Round 5
// 670.404 us; speedup vs baseline: 2.4432x; 1.0116x over previous
//
#include <hip/hip_runtime.h>
#include <hip/hip_bf16.h>
#include <math.h>

// Problem constants
#define Bsz 8
#define Lseq 2048
#define ENC_IN 21
#define C_OUT 21
#define D_MODEL 512
#define D_INNER 1024
#define D_STATE 16
#define D_CONV 4
#define DT_RANK 32
#define MARK_DIM 4
#define PRED_LEN 96
#define L_TAIL (Lseq - PRED_LEN)   // 1952
#define K_EMB 80                   // 63 conv taps + 4 mark + 13 zero-pad
#define CHUNK 128
#define NCHUNK_A 15                // chunks 0..14 in pass A; chunk 15 in pass B
#define MTOT (Bsz * Lseq)          // 16384

#define PE_C0 (-9.210340371976184f / (float)D_MODEL)   // -ln(10000)/d_model

// ---------------------------------------------------------------------------
// 1) Instance-norm stats: mean/std over time per (b, c)
// ---------------------------------------------------------------------------
__global__ void stats_kernel(const float* __restrict__ x_enc,
                             float* __restrict__ mean, float* __restrict__ stdv) {
    int bc = blockIdx.x;               // 0..167
    int b = bc / ENC_IN, c = bc % ENC_IN;
    __shared__ float red[256];
    int t = threadIdx.x;
    float s = 0.f;
    for (int l = t; l < Lseq; l += 256)
        s += x_enc[((size_t)b * Lseq + l) * ENC_IN + c];
    red[t] = s; __syncthreads();
    for (int off = 128; off > 0; off >>= 1) {
        if (t < off) red[t] += red[t + off];
        __syncthreads();
    }
    float m = red[0] / (float)Lseq;
    __syncthreads();
    float v = 0.f;
    for (int l = t; l < Lseq; l += 256) {
        float d = x_enc[((size_t)b * Lseq + l) * ENC_IN + c] - m;
        v += d * d;
    }
    red[t] = v; __syncthreads();
    for (int off = 128; off > 0; off >>= 1) {
        if (t < off) red[t] += red[t + off];
        __syncthreads();
    }
    if (t == 0) {
        mean[bc] = m;
        stdv[bc] = sqrtf(red[0] / (float)Lseq + 1e-5f);
    }
}

// ---------------------------------------------------------------------------
// 2) Fuse head_w @ out_proj_w -> W (21 x 1024)
// ---------------------------------------------------------------------------
__global__ void fuse_w_kernel(const float* __restrict__ head_w,
                              const float* __restrict__ out_proj_w,
                              float* __restrict__ W) {
    int idx = blockIdx.x * 256 + threadIdx.x;
    if (idx >= C_OUT * D_INNER) return;
    int c = idx / D_INNER, d = idx % D_INNER;
    float s = 0.f;
    for (int k = 0; k < D_MODEL; ++k)
        s += head_w[c * D_MODEL + k] * out_proj_w[(size_t)k * D_INNER + d];
    W[idx] = s;
}

// ---------------------------------------------------------------------------
// 3a) Pack embedding weights TRANSPOSED: WembT[k][d]
// ---------------------------------------------------------------------------
__global__ void prep_wT_kernel(const float* __restrict__ conv_w,
                               const float* __restrict__ temp_w,
                               float* __restrict__ WembT) {
    int idx = blockIdx.x * 256 + threadIdx.x;        // 80*512 exact
    int k = idx / D_MODEL, d = idx % D_MODEL;
    float v = 0.f;
    if (k < 3 * ENC_IN) {
        int kk = k / ENC_IN, c = k % ENC_IN;
        v = conv_w[((size_t)d * ENC_IN + c) * 3 + kk];
    } else if (k < 3 * ENC_IN + MARK_DIM) {
        v = temp_w[d * MARK_DIM + (k - 3 * ENC_IN)];
    }
    WembT[idx] = v;
}

// ---------------------------------------------------------------------------
// 3b) Build xinT[k][bl] (k-major): normalized circular taps + mark features
// ---------------------------------------------------------------------------
__global__ void prep_x_kernel(const float* __restrict__ x_enc,
                              const float* __restrict__ x_mark,
                              const float* __restrict__ mean,
                              const float* __restrict__ stdv,
                              float* __restrict__ xinT) {
    int idx = blockIdx.x * 256 + threadIdx.x;        // 80*16384 exact
    int k = idx >> 14, bl = idx & (MTOT - 1);
    int b = bl >> 11, l = bl & (Lseq - 1);
    float v = 0.f;
    if (k < 3 * ENC_IN) {
        int kk = k / ENC_IN, c = k % ENC_IN;
        int ll = (l + kk - 1 + Lseq) & (Lseq - 1);
        v = (x_enc[((size_t)b * Lseq + ll) * ENC_IN + c] - mean[b * ENC_IN + c])
            / stdv[b * ENC_IN + c];
    } else if (k < 3 * ENC_IN + MARK_DIM) {
        v = x_mark[((size_t)b * Lseq + l) * MARK_DIM + (k - 3 * ENC_IN)];
    }
    xinT[idx] = v;
}

// ---------------------------------------------------------------------------
// 3c) Wcomb[j][k] = sum_d in_proj_w[j][d] * WembT[k][d]   (2048 x 80)
// ---------------------------------------------------------------------------
__global__ void wcomb_kernel(const float* __restrict__ in_proj_w,
                             const float* __restrict__ WembT,
                             float* __restrict__ Wcomb) {
    int idx = blockIdx.x * 256 + threadIdx.x;        // 2048*80 exact
    int j = idx / K_EMB, k = idx % K_EMB;
    const float* a = in_proj_w + (size_t)j * D_MODEL;
    const float* b = WembT + (size_t)k * D_MODEL;
    float s = 0.f;
    for (int d = 0; d < D_MODEL; d += 4) {
        float4 av = *(const float4*)(a + d);
        float4 bv = *(const float4*)(b + d);
        s += av.x * bv.x + av.y * bv.y + av.z * bv.z + av.w * bv.w;
    }
    Wcomb[idx] = s;
}

// ---------------------------------------------------------------------------
// 3d) PEpZ[lz][j] = pe[1952+lz][:] . in_proj_w[1024+j][:]  (96 x 1024)
// ---------------------------------------------------------------------------
__global__ void pepz_kernel(const float* __restrict__ in_proj_w,
                            float* __restrict__ PEpZ) {
    __shared__ float per[D_MODEL];
    int lz = blockIdx.x;                  // 0..95
    int t = threadIdx.x;
    {
        int l = L_TAIL + lz;
        float div = __expf((float)(2 * t) * PE_C0);
        float s, c;
        sincosf((float)l * div, &s, &c);
        per[2 * t] = s;
        per[2 * t + 1] = c;
    }
    __syncthreads();
    for (int q = 0; q < 4; ++q) {
        int j = q * 256 + t;
        const float* w = in_proj_w + (size_t)(D_INNER + j) * D_MODEL;
        float s = 0.f;
        for (int d = 0; d < D_MODEL; d += 4) {
            float4 wv = *(const float4*)(w + d);
            s += per[d] * wv.x + per[d + 1] * wv.y + per[d + 2] * wv.z + per[d + 3] * wv.w;
        }
        PEpZ[(size_t)lz * D_INNER + j] = s;
    }
}

// ---------------------------------------------------------------------------
// 4) Templated fp32 tiled GEMM. C[M][N] (ld=N), BM=BN=64, BK=16, 256 thr.
//    AMODE 0: A[m*lda+k]   1: A[k*lda+m]   2: A[k*lda+blmap(m)] (tail remap)
//    BMODE 0: B[n*ldb+k]   1: B[k*ldb+n]   2: analytic PE, B[n=l][k=d]
//    EPI 0: none   1: +bias[row], softplus   2: +bias[row*2048+(col&2047)]
//    EPI 3: +bias[(row%96)*N+col]
// ---------------------------------------------------------------------------
template <int AMODE, int BMODE, int EPI>
__launch_bounds__(256)
__global__ void gemm(const float* __restrict__ A, const float* __restrict__ B,
                     float* __restrict__ C0, const float* __restrict__ bias,
                     int M, int N, int K, int lda, int ldb) {
    __shared__ float As[16][65];
    __shared__ float Bs[16][65];
    int bm = blockIdx.y, bn = blockIdx.x;
    int t = threadIdx.x;
    int tx = t & 15, ty = t >> 4;
    float acc[4][4] = {};
    int arow = bm * 64, bcol = bn * 64;
    int lr = t >> 2;          // row-major loader: 0..63 row, 4 along k
    int lk = (t & 3) * 4;
    int lrk = t >> 4;         // k-major loader: 0..15 k, 4 along m/n
    int lm4 = (t & 15) * 4;

    // hoisted per-thread source indices
    size_t acol = 0;
    if constexpr (AMODE == 2) {
        int m0 = arow + lm4;
        acol = (size_t)(m0 / PRED_LEN) * Lseq + L_TAIL + (m0 % PRED_LEN);
    } else if constexpr (AMODE == 1) {
        acol = (size_t)(arow + lm4);
    }

    for (int k0 = 0; k0 < K; k0 += 16) {
        // ---- A tile ----
        if constexpr (AMODE == 0) {
            float4 av = *(const float4*)(A + (size_t)(arow + lr) * lda + k0 + lk);
            As[lk + 0][lr] = av.x; As[lk + 1][lr] = av.y;
            As[lk + 2][lr] = av.z; As[lk + 3][lr] = av.w;
        } else {
            float4 av = *(const float4*)(A + (size_t)(k0 + lrk) * lda + acol);
            As[lrk][lm4 + 0] = av.x; As[lrk][lm4 + 1] = av.y;
            As[lrk][lm4 + 2] = av.z; As[lrk][lm4 + 3] = av.w;
        }
        // ---- B tile ----
        if constexpr (BMODE == 0) {
            float4 bv = *(const float4*)(B + (size_t)(bcol + lr) * ldb + k0 + lk);
            Bs[lk + 0][lr] = bv.x; Bs[lk + 1][lr] = bv.y;
            Bs[lk + 2][lr] = bv.z; Bs[lk + 3][lr] = bv.w;
        } else if constexpr (BMODE == 1) {
            float4 bv = *(const float4*)(B + (size_t)(k0 + lrk) * ldb + bcol + lm4);
            Bs[lrk][lm4 + 0] = bv.x; Bs[lrk][lm4 + 1] = bv.y;
            Bs[lrk][lm4 + 2] = bv.z; Bs[lrk][lm4 + 3] = bv.w;
        } else {
            // analytic PE: B[l][d] = (d even ? sin : cos)(l * exp(d_even*PE_C0))
            int d0 = k0 + lk;
            float l = (float)(bcol + lr);
            float e0 = __expf((float)d0 * PE_C0);
            float e1 = __expf((float)(d0 + 2) * PE_C0);
            float4 bv;
            sincosf(l * e0, &bv.x, &bv.y);
            sincosf(l * e1, &bv.z, &bv.w);
            Bs[lk + 0][lr] = bv.x; Bs[lk + 1][lr] = bv.y;
            Bs[lk + 2][lr] = bv.z; Bs[lk + 3][lr] = bv.w;
        }
        __syncthreads();
        #pragma unroll
        for (int kk = 0; kk < 16; ++kk) {
            float a[4], bq[4];
            #pragma unroll
            for (int i = 0; i < 4; ++i) a[i] = As[kk][ty * 4 + i];
            #pragma unroll
            for (int j = 0; j < 4; ++j) bq[j] = Bs[kk][tx * 4 + j];
            #pragma unroll
            for (int i = 0; i < 4; ++i)
                #pragma unroll
                for (int j = 0; j < 4; ++j)
                    acc[i][j] += a[i] * bq[j];
        }
        __syncthreads();
    }

    #pragma unroll
    for (int i = 0; i < 4; ++i) {
        int row = arow + ty * 4 + i;
        #pragma unroll
        for (int j = 0; j < 4; ++j) {
            int col = bcol + tx * 4 + j;
            float v = acc[i][j];
            if (EPI == 1) {
                v += bias[row];
                v = (v > 20.f) ? v : log1pf(__expf(v));
            }
            if (EPI == 2) {
                v += bias[(size_t)row * Lseq + (col & (Lseq - 1))];
            }
            if (EPI == 3) {
                v += bias[(size_t)(row % PRED_LEN) * N + col];
            }
            C0[(size_t)row * N + col] = v;
        }
    }
}

// ---------------------------------------------------------------------------
// 5) Depthwise causal conv1d (k=4) + SiLU on time-contiguous layout.
//    xs_rawT[d][bl] -> xs_convT[d][bl]; thread = 4 consecutive l of one d.
// ---------------------------------------------------------------------------
__global__ void dwconv_kernel(const float* __restrict__ xs_rawT,
                              const float* __restrict__ w,
                              const float* __restrict__ bias,
                              float* __restrict__ outT) {
    int bid = blockIdx.x;                 // 1024 d * 16 chunks
    int d = bid & (D_INNER - 1), ch = bid >> 10;
    int t = threadIdx.x;
    int lbase = ch * 1024 + t * 4;        // bl of first output
    const float* row = xs_rawT + (size_t)d * MTOT;
    float w0 = w[d * D_CONV + 0], w1 = w[d * D_CONV + 1];
    float w2 = w[d * D_CONV + 2], w3 = w[d * D_CONV + 3];
    float bs = bias[d];
    float4 cur = *(const float4*)(row + lbase);
    float4 pv = make_float4(0.f, 0.f, 0.f, 0.f);
    if (lbase >= 4) pv = *(const float4*)(row + lbase - 4);
    float v[7] = {pv.y, pv.z, pv.w, cur.x, cur.y, cur.z, cur.w};
    int lpos = lbase & (Lseq - 1);
    float o[4];
    if (lpos != 0) {                      // all taps in-batch (lpos multiple of 4)
        #pragma unroll
        for (int j = 0; j < 4; ++j)
            o[j] = bs + w0 * v[j] + w1 * v[j + 1] + w2 * v[j + 2] + w3 * v[j + 3];
    } else {                              // batch start: mask ll<0 taps
        #pragma unroll
        for (int j = 0; j < 4; ++j) {
            float acc = bs;
            #pragma unroll
            for (int k2 = 0; k2 < 4; ++k2) {
                int ll = j - 3 + k2;
                if (ll >= 0) acc += v[j + k2] * ((k2 == 0) ? w0 : (k2 == 1) ? w1 : (k2 == 2) ? w2 : w3);
            }
            o[j] = acc;
        }
    }
    float4 res;
    res.x = o[0] / (1.f + __expf(-o[0]));
    res.y = o[1] / (1.f + __expf(-o[1]));
    res.z = o[2] / (1.f + __expf(-o[2]));
    res.w = o[3] / (1.f + __expf(-o[3]));
    *(float4*)(outT + (size_t)d * MTOT + lbase) = res;
}

// ---------------------------------------------------------------------------
// 6a) Chunked scan, pass A (chunks 0..14): per-chunk (P, S).
//     Transposed inputs: one float4 per 4 timesteps.
// ---------------------------------------------------------------------------
__launch_bounds__(256)
__global__ void scanA_kernel(const float* __restrict__ deltaT,
                             const float* __restrict__ uT,
                             const float* __restrict__ xdblT,
                             const float* __restrict__ A_log,
                             float* __restrict__ Pa,
                             float* __restrict__ Sa) {
    int b = blockIdx.x >> 6;
    int dg = blockIdx.x & 63;
    int c = blockIdx.y;                 // 0..14
    int t = threadIdx.x;
    int d = dg * 16 + (t >> 4);
    int n = t & 15;
    float A = -__expf(A_log[d * D_STATE + n]);
    size_t base = (size_t)d * MTOT + b * Lseq + c * CHUNK;
    const float* pd = deltaT + base;
    const float* pu = uT + base;
    const float* pB = xdblT + (size_t)(DT_RANK + n) * MTOT + b * Lseq + c * CHUNK;
    float P = 1.f, S = 0.f;
    #pragma unroll 4
    for (int i = 0; i < CHUNK / 4; ++i) {
        float4 dv = *(const float4*)(pd + 4 * i);
        float4 uv = *(const float4*)(pu + 4 * i);
        float4 Bv = *(const float4*)(pB + 4 * i);
        float a;
        a = __expf(dv.x * A); P *= a; S = a * S + (dv.x * uv.x) * Bv.x;
        a = __expf(dv.y * A); P *= a; S = a * S + (dv.y * uv.y) * Bv.y;
        a = __expf(dv.z * A); P *= a; S = a * S + (dv.z * uv.z) * Bv.z;
        a = __expf(dv.w * A); P *= a; S = a * S + (dv.w * uv.w) * Bv.w;
    }
    size_t o = ((size_t)(b * NCHUNK_A + c) * 64 + dg) * 256 + t;
    Pa[o] = P;
    Sa[o] = S;
}

// ---------------------------------------------------------------------------
// 6b) Chunked scan, pass B: combine chunk factors, scan final chunk, emit y.
// ---------------------------------------------------------------------------
__launch_bounds__(256)
__global__ void scanB_kernel(const float* __restrict__ deltaT,
                             const float* __restrict__ uT,
                             const float* __restrict__ xdblT,
                             const float* __restrict__ A_log,
                             const float* __restrict__ Dp,
                             const float* __restrict__ Pa,
                             const float* __restrict__ Sa,
                             const float* __restrict__ z96,
                             float* __restrict__ y96) {
    int b = blockIdx.x >> 6;
    int dg = blockIdx.x & 63;
    int t = threadIdx.x;
    int d = dg * 16 + (t >> 4);
    int n = t & 15;
    float A = -__expf(A_log[d * D_STATE + n]);
    float Dd = Dp[d];
    float h = 0.f;
    for (int c = 0; c < NCHUNK_A; ++c) {
        size_t o = ((size_t)(b * NCHUNK_A + c) * 64 + dg) * 256 + t;
        h = Pa[o] * h + Sa[o];
    }
    const int lt0 = NCHUNK_A * CHUNK;     // 1920
    size_t base = (size_t)d * MTOT + b * Lseq + lt0;
    const float* pd = deltaT + base;
    const float* pu = uT + base;
    const float* pB = xdblT + (size_t)(DT_RANK + n) * MTOT + b * Lseq + lt0;
    const float* pC = xdblT + (size_t)(DT_RANK + D_STATE + n) * MTOT + b * Lseq + lt0;

    // l = 1920..1951: update only (no emission)
    #pragma unroll 2
    for (int i = 0; i < 8; ++i) {
        float4 dv = *(const float4*)(pd + 4 * i);
        float4 uv = *(const float4*)(pu + 4 * i);
        float4 Bv = *(const float4*)(pB + 4 * i);
        float a;
        a = __expf(dv.x * A); h = a * h + (dv.x * uv.x) * Bv.x;
        a = __expf(dv.y * A); h = a * h + (dv.y * uv.y) * Bv.y;
        a = __expf(dv.z * A); h = a * h + (dv.z * uv.z) * Bv.z;
        a = __expf(dv.w * A); h = a * h + (dv.w * uv.w) * Bv.w;
    }
    // l = 1952..2047: update + emit
    for (int i = 8; i < 32; ++i) {
        float4 dv = *(const float4*)(pd + 4 * i);
        float4 uv = *(const float4*)(pu + 4 * i);
        float4 Bv = *(const float4*)(pB + 4 * i);
        float4 Cv = *(const float4*)(pC + 4 * i);
        #pragma unroll
        for (int j = 0; j < 4; ++j) {
            float dl = (j == 0) ? dv.x : (j == 1) ? dv.y : (j == 2) ? dv.z : dv.w;
            float uu = (j == 0) ? uv.x : (j == 1) ? uv.y : (j == 2) ? uv.z : uv.w;
            float Bb = (j == 0) ? Bv.x : (j == 1) ? Bv.y : (j == 2) ? Bv.z : Bv.w;
            float Cc = (j == 0) ? Cv.x : (j == 1) ? Cv.y : (j == 2) ? Cv.z : Cv.w;
            float a = __expf(dl * A);
            h = a * h + (dl * uu) * Bb;
            float y = h * Cc;
            #pragma unroll
            for (int m = 8; m >= 1; m >>= 1) y += __shfl_xor(y, m, 16);
            if (n == 0) {
                int lz = (lt0 + 4 * i + j) - L_TAIL;   // 0..95
                size_t o = ((size_t)b * PRED_LEN + lz) * D_INNER + d;
                float z = z96[o];
                y96[o] = (y + uu * Dd) * (z / (1.f + __expf(-z)));
            }
        }
    }
}

// ---------------------------------------------------------------------------
// 7) Final head: out[b,t,c] = (y96[b,t,:] . W[c,:]) * std[b,c] + mean[b,c]
// ---------------------------------------------------------------------------
__global__ void head_kernel(const float* __restrict__ y96,
                            const float* __restrict__ W,
                            const float* __restrict__ mean,
                            const float* __restrict__ stdv,
                            float* __restrict__ out) {
    int idx = blockIdx.x;                 // 8*96*21
    int c = idx % C_OUT;
    int bt = idx / C_OUT;
    int b = bt / PRED_LEN;
    int lane = threadIdx.x;
    const float* yrow = y96 + (size_t)bt * D_INNER;
    const float* wrow = W + (size_t)c * D_INNER;
    float s = 0.f;
    for (int d = lane; d < D_INNER; d += 64) s += yrow[d] * wrow[d];
    #pragma unroll
    for (int m = 32; m >= 1; m >>= 1) s += __shfl_xor(s, m, 64);
    if (lane == 0)
        out[(size_t)bt * C_OUT + c] = s * stdv[b * C_OUT + c] + mean[b * C_OUT + c];
}

// ---------------------------------------------------------------------------
extern "C" void kernel_launch(void* const* d_in, const int* in_sizes, int n_in,
                              void* d_out, int out_size, void* d_ws, size_t ws_size,
                              hipStream_t stream) {
    const float* x_enc     = (const float*)d_in[0];
    const float* x_mark    = (const float*)d_in[1];
    const float* conv_w    = (const float*)d_in[4];
    const float* temp_w    = (const float*)d_in[5];
    const float* in_proj_w = (const float*)d_in[6];
    const float* conv1d_w  = (const float*)d_in[7];
    const float* conv1d_b  = (const float*)d_in[8];
    const float* x_proj_w  = (const float*)d_in[9];
    const float* dt_proj_w = (const float*)d_in[10];
    const float* dt_proj_b = (const float*)d_in[11];
    const float* A_log     = (const float*)d_in[12];
    const float* Dp        = (const float*)d_in[13];
    const float* out_proj_w= (const float*)d_in[14];
    const float* head_w    = (const float*)d_in[15];
    float* out = (float*)d_out;
    float* ws = (float*)d_ws;

    // workspace layout (floats) — NO aliasing. ~60.6M floats = 242.5 MB.
    size_t off = 0;
    float* mean     = ws + off; off += 256;
    float* stdv     = ws + off; off += 256;
    float* W        = ws + off; off += (size_t)C_OUT * D_INNER;            // 21504
    float* WembT    = ws + off; off += (size_t)K_EMB * D_MODEL;            // 40960
    float* Wcomb    = ws + off; off += (size_t)2 * D_INNER * K_EMB;        // 163840
    float* PEpT     = ws + off; off += (size_t)D_INNER * Lseq;             // 2.10M
    float* PEpZ     = ws + off; off += (size_t)PRED_LEN * D_INNER;         // 98304
    float* xinT     = ws + off; off += (size_t)K_EMB * MTOT;               // 1.31M
    float* xs_rawT  = ws + off; off += (size_t)D_INNER * MTOT;             // 16.8M
    float* z96      = ws + off; off += (size_t)Bsz * PRED_LEN * D_INNER;   // 0.79M
    float* xs_convT = ws + off; off += (size_t)D_INNER * MTOT;             // 16.8M
    float* xdblT    = ws + off; off += (size_t)64 * MTOT;                  // 1.05M
    float* deltaT   = ws + off; off += (size_t)D_INNER * MTOT;             // 16.8M
    float* Pa       = ws + off; off += (size_t)Bsz * NCHUNK_A * D_INNER * D_STATE; // 1.97M
    float* Sa       = ws + off; off += (size_t)Bsz * NCHUNK_A * D_INNER * D_STATE; // 1.97M
    float* y96      = ws + off; off += (size_t)Bsz * PRED_LEN * D_INNER;   // 0.79M

    // 1) instance-norm stats
    stats_kernel<<<Bsz * ENC_IN, 256, 0, stream>>>(x_enc, mean, stdv);
    // 2) fused output weight
    fuse_w_kernel<<<(C_OUT * D_INNER + 255) / 256, 256, 0, stream>>>(head_w, out_proj_w, W);
    // 3) precomputations
    prep_wT_kernel<<<(K_EMB * D_MODEL) / 256, 256, 0, stream>>>(conv_w, temp_w, WembT);
    prep_x_kernel<<<(K_EMB * MTOT) / 256, 256, 0, stream>>>(x_enc, x_mark, mean, stdv, xinT);
    wcomb_kernel<<<(2 * D_INNER * K_EMB) / 256, 256, 0, stream>>>(in_proj_w, WembT, Wcomb);
    pepz_kernel<<<PRED_LEN, 256, 0, stream>>>(in_proj_w, PEpZ);
    // PEpT[j][l] = in_proj_xs @ pe^T (analytic B)
    gemm<0, 2, 0><<<dim3(Lseq / 64, D_INNER / 64), 256, 0, stream>>>(
        in_proj_w, nullptr, PEpT, nullptr, D_INNER, Lseq, D_MODEL, D_MODEL, 0);
    // 4a) xs_rawT[j][bl] = Wcomb_xs @ xinT + PEpT[j][l]
    gemm<0, 1, 2><<<dim3(MTOT / 64, D_INNER / 64), 256, 0, stream>>>(
        Wcomb, xinT, xs_rawT, PEpT, D_INNER, MTOT, K_EMB, K_EMB, MTOT);
    // 4b) z96[bt][d] = xinT(tail-remap)^T @ Wcomb_z^T + PEpZ[bt%96][d]
    gemm<2, 0, 3><<<dim3(D_INNER / 64, (Bsz * PRED_LEN) / 64), 256, 0, stream>>>(
        xinT, Wcomb + (size_t)D_INNER * K_EMB, z96, PEpZ,
        Bsz * PRED_LEN, D_INNER, K_EMB, MTOT, K_EMB);
    // 5) depthwise causal conv + SiLU (time-contiguous)
    dwconv_kernel<<<D_INNER * 16, 256, 0, stream>>>(xs_rawT, conv1d_w, conv1d_b, xs_convT);
    // 6) xdblT[p][bl] = x_proj_w @ xs_convT
    gemm<0, 1, 0><<<dim3(MTOT / 64, 1), 256, 0, stream>>>(
        x_proj_w, xs_convT, xdblT, nullptr, 64, MTOT, D_INNER, D_INNER, MTOT);
    // 7) deltaT[d][bl] = softplus(dt_proj_w @ xdblT[:32] + dt_b[d])
    gemm<0, 1, 1><<<dim3(MTOT / 64, D_INNER / 64), 256, 0, stream>>>(
        dt_proj_w, xdblT, deltaT, dt_proj_b, D_INNER, MTOT, DT_RANK, DT_RANK, MTOT);
    // 8) chunked selective scan
    scanA_kernel<<<dim3(Bsz * 64, NCHUNK_A), 256, 0, stream>>>(
        deltaT, xs_convT, xdblT, A_log, Pa, Sa);
    scanB_kernel<<<Bsz * 64, 256, 0, stream>>>(
        deltaT, xs_convT, xdblT, A_log, Dp, Pa, Sa, z96, y96);
    // 9) head + de-normalize
    head_kernel<<<Bsz * PRED_LEN * C_OUT, 64, 0, stream>>>(y96, W, mean, stdv, out);
}

// Round 6
// 611.706 us; speedup vs baseline: 2.6777x; 1.0960x over previous
//
#include <hip/hip_runtime.h>
#include <hip/hip_bf16.h>
#include <math.h>

// Problem constants
#define Bsz 8
#define Lseq 2048
#define ENC_IN 21
#define C_OUT 21
#define D_MODEL 512
#define D_INNER 1024
#define D_STATE 16
#define D_CONV 4
#define DT_RANK 32
#define MARK_DIM 4
#define PRED_LEN 96
#define L_TAIL (Lseq - PRED_LEN)   // 1952
#define K_EMB 80                   // 63 conv taps + 4 mark + 13 zero-pad
#define CHUNK 128
#define NCHUNK_A 15                // chunks 0..14 in pass A; chunk 15 in pass B
#define MTOT (Bsz * Lseq)          // 16384

#define PE_C0 (-9.210340371976184f / (float)D_MODEL)   // -ln(10000)/d_model

// ---------------------------------------------------------------------------
// 1) Instance-norm stats: mean/std over time per (b, c)
// ---------------------------------------------------------------------------
__global__ void stats_kernel(const float* __restrict__ x_enc,
                             float* __restrict__ mean, float* __restrict__ stdv) {
    int bc = blockIdx.x;               // 0..167
    int b = bc / ENC_IN, c = bc % ENC_IN;
    __shared__ float red[256];
    int t = threadIdx.x;
    float s = 0.f;
    for (int l = t; l < Lseq; l += 256)
        s += x_enc[((size_t)b * Lseq + l) * ENC_IN + c];
    red[t] = s; __syncthreads();
    for (int off = 128; off > 0; off >>= 1) {
        if (t < off) red[t] += red[t + off];
        __syncthreads();
    }
    float m = red[0] / (float)Lseq;
    __syncthreads();
    float v = 0.f;
    for (int l = t; l < Lseq; l += 256) {
        float d = x_enc[((size_t)b * Lseq + l) * ENC_IN + c] - m;
        v += d * d;
    }
    red[t] = v; __syncthreads();
    for (int off = 128; off > 0; off >>= 1) {
        if (t < off) red[t] += red[t + off];
        __syncthreads();
    }
    if (t == 0) {
        mean[bc] = m;
        stdv[bc] = sqrtf(red[0] / (float)Lseq + 1e-5f);
    }
}

// ---------------------------------------------------------------------------
// 2) Fuse head_w @ out_proj_w -> W (21 x 1024)
// ---------------------------------------------------------------------------
__global__ void fuse_w_kernel(const float* __restrict__ head_w,
                              const float* __restrict__ out_proj_w,
                              float* __restrict__ W) {
    int idx = blockIdx.x * 256 + threadIdx.x;
    if (idx >= C_OUT * D_INNER) return;
    int c = idx / D_INNER, d = idx % D_INNER;
    float s = 0.f;
    for (int k = 0; k < D_MODEL; ++k)
        s += head_w[c * D_MODEL + k] * out_proj_w[(size_t)k * D_INNER + d];
    W[idx] = s;
}

// ---------------------------------------------------------------------------
// 3a) Pack embedding weights TRANSPOSED: WembT[k][d]
// ---------------------------------------------------------------------------
__global__ void prep_wT_kernel(const float* __restrict__ conv_w,
                               const float* __restrict__ temp_w,
                               float* __restrict__ WembT) {
    int idx = blockIdx.x * 256 + threadIdx.x;        // 80*512 exact
    int k = idx / D_MODEL, d = idx % D_MODEL;
    float v = 0.f;
    if (k < 3 * ENC_IN) {
        int kk = k / ENC_IN, c = k % ENC_IN;
        v = conv_w[((size_t)d * ENC_IN + c) * 3 + kk];
    } else if (k < 3 * ENC_IN + MARK_DIM) {
        v = temp_w[d * MARK_DIM + (k - 3 * ENC_IN)];
    }
    WembT[idx] = v;
}

// ---------------------------------------------------------------------------
// 3b) Build xinT[k][bl] (k-major): normalized circular taps + mark features
// ---------------------------------------------------------------------------
__global__ void prep_x_kernel(const float* __restrict__ x_enc,
                              const float* __restrict__ x_mark,
                              const float* __restrict__ mean,
                              const float* __restrict__ stdv,
                              float* __restrict__ xinT) {
    int idx = blockIdx.x * 256 + threadIdx.x;        // 80*16384 exact
    int k = idx >> 14, bl = idx & (MTOT - 1);
    int b = bl >> 11, l = bl & (Lseq - 1);
    float v = 0.f;
    if (k < 3 * ENC_IN) {
        int kk = k / ENC_IN, c = k % ENC_IN;
        int ll = (l + kk - 1 + Lseq) & (Lseq - 1);
        v = (x_enc[((size_t)b * Lseq + ll) * ENC_IN + c] - mean[b * ENC_IN + c])
            / stdv[b * ENC_IN + c];
    } else if (k < 3 * ENC_IN + MARK_DIM) {
        v = x_mark[((size_t)b * Lseq + l) * MARK_DIM + (k - 3 * ENC_IN)];
    }
    xinT[idx] = v;
}

// ---------------------------------------------------------------------------
// 3c) Wcomb[j][k] = sum_d in_proj_w[j][d] * WembT[k][d]   (2048 x 80)
// ---------------------------------------------------------------------------
__global__ void wcomb_kernel(const float* __restrict__ in_proj_w,
                             const float* __restrict__ WembT,
                             float* __restrict__ Wcomb) {
    int idx = blockIdx.x * 256 + threadIdx.x;        // 2048*80 exact
    int j = idx / K_EMB, k = idx % K_EMB;
    const float* a = in_proj_w + (size_t)j * D_MODEL;
    const float* b = WembT + (size_t)k * D_MODEL;
    float s = 0.f;
    for (int d = 0; d < D_MODEL; d += 4) {
        float4 av = *(const float4*)(a + d);
        float4 bv = *(const float4*)(b + d);
        s += av.x * bv.x + av.y * bv.y + av.z * bv.z + av.w * bv.w;
    }
    Wcomb[idx] = s;
}

// ---------------------------------------------------------------------------
// 3d) PEpZ[lz][j] = pe[1952+lz][:] . in_proj_w[1024+j][:]  (96 x 1024)
// ---------------------------------------------------------------------------
__global__ void pepz_kernel(const float* __restrict__ in_proj_w,
                            float* __restrict__ PEpZ) {
    __shared__ float per[D_MODEL];
    int lz = blockIdx.x;                  // 0..95
    int t = threadIdx.x;
    {
        int l = L_TAIL + lz;
        float div = __expf((float)(2 * t) * PE_C0);
        float s, c;
        sincosf((float)l * div, &s, &c);
        per[2 * t] = s;
        per[2 * t + 1] = c;
    }
    __syncthreads();
    for (int q = 0; q < 4; ++q) {
        int j = q * 256 + t;
        const float* w = in_proj_w + (size_t)(D_INNER + j) * D_MODEL;
        float s = 0.f;
        for (int d = 0; d < D_MODEL; d += 4) {
            float4 wv = *(const float4*)(w + d);
            s += per[d] * wv.x + per[d + 1] * wv.y + per[d + 2] * wv.z + per[d + 3] * wv.w;
        }
        PEpZ[(size_t)lz * D_INNER + j] = s;
    }
}

// ---------------------------------------------------------------------------
// 4) Templated fp32 tiled GEMM. C[M][N] (ld=N), BM=BN=64, BK=16, 256 thr.
//    AMODE 0: A[m*lda+k]   1: A[k*lda+m]   2: A[k*lda+blmap(m)] (tail remap)
//    BMODE 0: B[n*ldb+k]   1: B[k*ldb+n]   2: analytic PE, B[n=l][k=d]
//    EPI 0: none   1: +bias[row], softplus   2: +bias[row*2048+(col&2047)]
//    EPI 3: +bias[(row%96)*N+col]
// ---------------------------------------------------------------------------
template <int AMODE, int BMODE, int EPI>
__launch_bounds__(256)
__global__ void gemm(const float* __restrict__ A, const float* __restrict__ B,
                     float* __restrict__ C0, const float* __restrict__ bias,
                     int M, int N, int K, int lda, int ldb) {
    __shared__ float As[16][65];
    __shared__ float Bs[16][65];
    int bm = blockIdx.y, bn = blockIdx.x;
    int t = threadIdx.x;
    int tx = t & 15, ty = t >> 4;
    float acc[4][4] = {};
    int arow = bm * 64, bcol = bn * 64;
    int lr = t >> 2;          // row-major loader: 0..63 row, 4 along k
    int lk = (t & 3) * 4;
    int lrk = t >> 4;         // k-major loader: 0..15 k, 4 along m/n
    int lm4 = (t & 15) * 4;

    size_t acol = 0;
    if constexpr (AMODE == 2) {
        int m0 = arow + lm4;
        acol = (size_t)(m0 / PRED_LEN) * Lseq + L_TAIL + (m0 % PRED_LEN);
    } else if constexpr (AMODE == 1) {
        acol = (size_t)(arow + lm4);
    }

    for (int k0 = 0; k0 < K; k0 += 16) {
        // ---- A tile ----
        if constexpr (AMODE == 0) {
            float4 av = *(const float4*)(A + (size_t)(arow + lr) * lda + k0 + lk);
            As[lk + 0][lr] = av.x; As[lk + 1][lr] = av.y;
            As[lk + 2][lr] = av.z; As[lk + 3][lr] = av.w;
        } else {
            float4 av = *(const float4*)(A + (size_t)(k0 + lrk) * lda + acol);
            As[lrk][lm4 + 0] = av.x; As[lrk][lm4 + 1] = av.y;
            As[lrk][lm4 + 2] = av.z; As[lrk][lm4 + 3] = av.w;
        }
        // ---- B tile ----
        if constexpr (BMODE == 0) {
            float4 bv = *(const float4*)(B + (size_t)(bcol + lr) * ldb + k0 + lk);
            Bs[lk + 0][lr] = bv.x; Bs[lk + 1][lr] = bv.y;
            Bs[lk + 2][lr] = bv.z; Bs[lk + 3][lr] = bv.w;
        } else if constexpr (BMODE == 1) {
            float4 bv = *(const float4*)(B + (size_t)(k0 + lrk) * ldb + bcol + lm4);
            Bs[lrk][lm4 + 0] = bv.x; Bs[lrk][lm4 + 1] = bv.y;
            Bs[lrk][lm4 + 2] = bv.z; Bs[lrk][lm4 + 3] = bv.w;
        } else {
            int d0 = k0 + lk;
            float l = (float)(bcol + lr);
            float e0 = __expf((float)d0 * PE_C0);
            float e1 = __expf((float)(d0 + 2) * PE_C0);
            float4 bv;
            sincosf(l * e0, &bv.x, &bv.y);
            sincosf(l * e1, &bv.z, &bv.w);
            Bs[lk + 0][lr] = bv.x; Bs[lk + 1][lr] = bv.y;
            Bs[lk + 2][lr] = bv.z; Bs[lk + 3][lr] = bv.w;
        }
        __syncthreads();
        #pragma unroll
        for (int kk = 0; kk < 16; ++kk) {
            float a[4], bq[4];
            #pragma unroll
            for (int i = 0; i < 4; ++i) a[i] = As[kk][ty * 4 + i];
            #pragma unroll
            for (int j = 0; j < 4; ++j) bq[j] = Bs[kk][tx * 4 + j];
            #pragma unroll
            for (int i = 0; i < 4; ++i)
                #pragma unroll
                for (int j = 0; j < 4; ++j)
                    acc[i][j] += a[i] * bq[j];
        }
        __syncthreads();
    }

    #pragma unroll
    for (int i = 0; i < 4; ++i) {
        int row = arow + ty * 4 + i;
        #pragma unroll
        for (int j = 0; j < 4; ++j) {
            int col = bcol + tx * 4 + j;
            float v = acc[i][j];
            if (EPI == 1) {
                v += bias[row];
                v = (v > 20.f) ? v : log1pf(__expf(v));
            }
            if (EPI == 2) {
                v += bias[(size_t)row * Lseq + (col & (Lseq - 1))];
            }
            if (EPI == 3) {
                v += bias[(size_t)(row % PRED_LEN) * N + col];
            }
            C0[(size_t)row * N + col] = v;
        }
    }
}

// ---------------------------------------------------------------------------
// 5) Depthwise causal conv1d (k=4) + SiLU on time-contiguous layout.
// ---------------------------------------------------------------------------
__global__ void dwconv_kernel(const float* __restrict__ xs_rawT,
                              const float* __restrict__ w,
                              const float* __restrict__ bias,
                              float* __restrict__ outT) {
    int bid = blockIdx.x;                 // 1024 d * 16 chunks
    int d = bid & (D_INNER - 1), ch = bid >> 10;
    int t = threadIdx.x;
    int lbase = ch * 1024 + t * 4;        // bl of first output
    const float* row = xs_rawT + (size_t)d * MTOT;
    float w0 = w[d * D_CONV + 0], w1 = w[d * D_CONV + 1];
    float w2 = w[d * D_CONV + 2], w3 = w[d * D_CONV + 3];
    float bs = bias[d];
    float4 cur = *(const float4*)(row + lbase);
    float4 pv = make_float4(0.f, 0.f, 0.f, 0.f);
    if (lbase >= 4) pv = *(const float4*)(row + lbase - 4);
    float v[7] = {pv.y, pv.z, pv.w, cur.x, cur.y, cur.z, cur.w};
    int lpos = lbase & (Lseq - 1);
    float o[4];
    if (lpos != 0) {
        #pragma unroll
        for (int j = 0; j < 4; ++j)
            o[j] = bs + w0 * v[j] + w1 * v[j + 1] + w2 * v[j + 2] + w3 * v[j + 3];
    } else {
        #pragma unroll
        for (int j = 0; j < 4; ++j) {
            float acc = bs;
            #pragma unroll
            for (int k2 = 0; k2 < 4; ++k2) {
                int ll = j - 3 + k2;
                if (ll >= 0) acc += v[j + k2] * ((k2 == 0) ? w0 : (k2 == 1) ? w1 : (k2 == 2) ? w2 : w3);
            }
            o[j] = acc;
        }
    }
    float4 res;
    res.x = o[0] / (1.f + __expf(-o[0]));
    res.y = o[1] / (1.f + __expf(-o[1]));
    res.z = o[2] / (1.f + __expf(-o[2]));
    res.w = o[3] / (1.f + __expf(-o[3]));
    *(float4*)(outT + (size_t)d * MTOT + lbase) = res;
}

// ---------------------------------------------------------------------------
// 6a) Chunked scan, pass A (chunks 0..14): per-chunk (P, S).
//     4 independent d-chains per thread (ILP); B-load amortized across chains.
//     Pa/Sa layout: [(b*15+c)*1024 + d]*16 + n.
// ---------------------------------------------------------------------------
__launch_bounds__(256, 4)
__global__ void scanA_kernel(const float* __restrict__ deltaT,
                             const float* __restrict__ uT,
                             const float* __restrict__ xdblT,
                             const float* __restrict__ A_log,
                             float* __restrict__ Pa,
                             float* __restrict__ Sa) {
    int b = blockIdx.x >> 4;            // 0..7
    int dg = blockIdx.x & 15;           // 0..15 (64 d's per block)
    int c = blockIdx.y;                 // 0..14
    int t = threadIdx.x;
    int dgrp = t >> 4, n = t & 15;
    int d0 = dg * 64 + dgrp;            // chains at d0 + 16*vd

    float A[4], P[4], S[4];
    const float *pd[4], *pu[4];
    #pragma unroll
    for (int vd = 0; vd < 4; ++vd) {
        int d = d0 + 16 * vd;
        A[vd] = -__expf(A_log[d * D_STATE + n]);
        P[vd] = 1.f; S[vd] = 0.f;
        size_t base = (size_t)d * MTOT + b * Lseq + c * CHUNK;
        pd[vd] = deltaT + base;
        pu[vd] = uT + base;
    }
    const float* pB = xdblT + (size_t)(DT_RANK + n) * MTOT + b * Lseq + c * CHUNK;

    for (int i = 0; i < CHUNK / 4; ++i) {
        float4 Bv = *(const float4*)(pB + 4 * i);
        float4 dv[4], uv[4];
        #pragma unroll
        for (int vd = 0; vd < 4; ++vd) {
            dv[vd] = *(const float4*)(pd[vd] + 4 * i);
            uv[vd] = *(const float4*)(pu[vd] + 4 * i);
        }
        #pragma unroll
        for (int vd = 0; vd < 4; ++vd) {
            float a;
            a = __expf(dv[vd].x * A[vd]); P[vd] *= a; S[vd] = a * S[vd] + (dv[vd].x * uv[vd].x) * Bv.x;
            a = __expf(dv[vd].y * A[vd]); P[vd] *= a; S[vd] = a * S[vd] + (dv[vd].y * uv[vd].y) * Bv.y;
            a = __expf(dv[vd].z * A[vd]); P[vd] *= a; S[vd] = a * S[vd] + (dv[vd].z * uv[vd].z) * Bv.z;
            a = __expf(dv[vd].w * A[vd]); P[vd] *= a; S[vd] = a * S[vd] + (dv[vd].w * uv[vd].w) * Bv.w;
        }
    }
    #pragma unroll
    for (int vd = 0; vd < 4; ++vd) {
        int d = d0 + 16 * vd;
        size_t o = ((size_t)(b * NCHUNK_A + c) * D_INNER + d) * 16 + n;
        Pa[o] = P[vd];
        Sa[o] = S[vd];
    }
}

// ---------------------------------------------------------------------------
// 6b) Chunked scan, pass B: combine chunk factors, scan final chunk, emit y.
// ---------------------------------------------------------------------------
__launch_bounds__(256)
__global__ void scanB_kernel(const float* __restrict__ deltaT,
                             const float* __restrict__ uT,
                             const float* __restrict__ xdblT,
                             const float* __restrict__ A_log,
                             const float* __restrict__ Dp,
                             const float* __restrict__ Pa,
                             const float* __restrict__ Sa,
                             const float* __restrict__ z96,
                             float* __restrict__ y96) {
    int b = blockIdx.x >> 6;
    int dg = blockIdx.x & 63;
    int t = threadIdx.x;
    int d = dg * 16 + (t >> 4);
    int n = t & 15;
    float A = -__expf(A_log[d * D_STATE + n]);
    float Dd = Dp[d];
    float h = 0.f;
    for (int c = 0; c < NCHUNK_A; ++c) {
        size_t o = ((size_t)(b * NCHUNK_A + c) * D_INNER + d) * 16 + n;
        h = Pa[o] * h + Sa[o];
    }
    const int lt0 = NCHUNK_A * CHUNK;     // 1920
    size_t base = (size_t)d * MTOT + b * Lseq + lt0;
    const float* pd = deltaT + base;
    const float* pu = uT + base;
    const float* pB = xdblT + (size_t)(DT_RANK + n) * MTOT + b * Lseq + lt0;
    const float* pC = xdblT + (size_t)(DT_RANK + D_STATE + n) * MTOT + b * Lseq + lt0;

    // l = 1920..1951: update only
    #pragma unroll 2
    for (int i = 0; i < 8; ++i) {
        float4 dv = *(const float4*)(pd + 4 * i);
        float4 uv = *(const float4*)(pu + 4 * i);
        float4 Bv = *(const float4*)(pB + 4 * i);
        float a;
        a = __expf(dv.x * A); h = a * h + (dv.x * uv.x) * Bv.x;
        a = __expf(dv.y * A); h = a * h + (dv.y * uv.y) * Bv.y;
        a = __expf(dv.z * A); h = a * h + (dv.z * uv.z) * Bv.z;
        a = __expf(dv.w * A); h = a * h + (dv.w * uv.w) * Bv.w;
    }
    // l = 1952..2047: update + emit
    for (int i = 8; i < 32; ++i) {
        float4 dv = *(const float4*)(pd + 4 * i);
        float4 uv = *(const float4*)(pu + 4 * i);
        float4 Bv = *(const float4*)(pB + 4 * i);
        float4 Cv = *(const float4*)(pC + 4 * i);
        #pragma unroll
        for (int j = 0; j < 4; ++j) {
            float dl = (j == 0) ? dv.x : (j == 1) ? dv.y : (j == 2) ? dv.z : dv.w;
            float uu = (j == 0) ? uv.x : (j == 1) ? uv.y : (j == 2) ? uv.z : uv.w;
            float Bb = (j == 0) ? Bv.x : (j == 1) ? Bv.y : (j == 2) ? Bv.z : Bv.w;
            float Cc = (j == 0) ? Cv.x : (j == 1) ? Cv.y : (j == 2) ? Cv.z : Cv.w;
            float a = __expf(dl * A);
            h = a * h + (dl * uu) * Bb;
            float y = h * Cc;
            #pragma unroll
            for (int m = 8; m >= 1; m >>= 1) y += __shfl_xor(y, m, 16);
            if (n == 0) {
                int lz = (lt0 + 4 * i + j) - L_TAIL;   // 0..95
                size_t o = ((size_t)b * PRED_LEN + lz) * D_INNER + d;
                float z = z96[o];
                y96[o] = (y + uu * Dd) * (z / (1.f + __expf(-z)));
            }
        }
    }
}

// ---------------------------------------------------------------------------
// 7) Final head: out[b,t,c] = (y96[b,t,:] . W[c,:]) * std[b,c] + mean[b,c]
// ---------------------------------------------------------------------------
__global__ void head_kernel(const float* __restrict__ y96,
                            const float* __restrict__ W,
                            const float* __restrict__ mean,
                            const float* __restrict__ stdv,
                            float* __restrict__ out) {
    int idx = blockIdx.x;                 // 8*96*21
    int c = idx % C_OUT;
    int bt = idx / C_OUT;
    int b = bt / PRED_LEN;
    int lane = threadIdx.x;
    const float* yrow = y96 + (size_t)bt * D_INNER;
    const float* wrow = W + (size_t)c * D_INNER;
    float s = 0.f;
    for (int d = lane; d < D_INNER; d += 64) s += yrow[d] * wrow[d];
    #pragma unroll
    for (int m = 32; m >= 1; m >>= 1) s += __shfl_xor(s, m, 64);
    if (lane == 0)
        out[(size_t)bt * C_OUT + c] = s * stdv[b * C_OUT + c] + mean[b * C_OUT + c];
}

// ---------------------------------------------------------------------------
extern "C" void kernel_launch(void* const* d_in, const int* in_sizes, int n_in,
                              void* d_out, int out_size, void* d_ws, size_t ws_size,
                              hipStream_t stream) {
    const float* x_enc     = (const float*)d_in[0];
    const float* x_mark    = (const float*)d_in[1];
    const float* conv_w    = (const float*)d_in[4];
    const float* temp_w    = (const float*)d_in[5];
    const float* in_proj_w = (const float*)d_in[6];
    const float* conv1d_w  = (const float*)d_in[7];
    const float* conv1d_b  = (const float*)d_in[8];
    const float* x_proj_w  = (const float*)d_in[9];
    const float* dt_proj_w = (const float*)d_in[10];
    const float* dt_proj_b = (const float*)d_in[11];
    const float* A_log     = (const float*)d_in[12];
    const float* Dp        = (const float*)d_in[13];
    const float* out_proj_w= (const float*)d_in[14];
    const float* head_w    = (const float*)d_in[15];
    float* out = (float*)d_out;
    float* ws = (float*)d_ws;

    // workspace layout (floats) — NO aliasing. ~60.6M floats = 242.5 MB.
    size_t off = 0;
    float* mean     = ws + off; off += 256;
    float* stdv     = ws + off; off += 256;
    float* W        = ws + off; off += (size_t)C_OUT * D_INNER;            // 21504
    float* WembT    = ws + off; off += (size_t)K_EMB * D_MODEL;            // 40960
    float* Wcomb    = ws + off; off += (size_t)2 * D_INNER * K_EMB;        // 163840
    float* PEpT     = ws + off; off += (size_t)D_INNER * Lseq;             // 2.10M
    float* PEpZ     = ws + off; off += (size_t)PRED_LEN * D_INNER;         // 98304
    float* xinT     = ws + off; off += (size_t)K_EMB * MTOT;               // 1.31M
    float* xs_rawT  = ws + off; off += (size_t)D_INNER * MTOT;             // 16.8M
    float* z96      = ws + off; off += (size_t)Bsz * PRED_LEN * D_INNER;   // 0.79M
    float* xs_convT = ws + off; off += (size_t)D_INNER * MTOT;             // 16.8M
    float* xdblT    = ws + off; off += (size_t)64 * MTOT;                  // 1.05M
    float* deltaT   = ws + off; off += (size_t)D_INNER * MTOT;             // 16.8M
    float* Pa       = ws + off; off += (size_t)Bsz * NCHUNK_A * D_INNER * D_STATE; // 1.97M
    float* Sa       = ws + off; off += (size_t)Bsz * NCHUNK_A * D_INNER * D_STATE; // 1.97M
    float* y96      = ws + off; off += (size_t)Bsz * PRED_LEN * D_INNER;   // 0.79M

    // 1) instance-norm stats
    stats_kernel<<<Bsz * ENC_IN, 256, 0, stream>>>(x_enc, mean, stdv);
    // 2) fused output weight
    fuse_w_kernel<<<(C_OUT * D_INNER + 255) / 256, 256, 0, stream>>>(head_w, out_proj_w, W);
    // 3) precomputations
    prep_wT_kernel<<<(K_EMB * D_MODEL) / 256, 256, 0, stream>>>(conv_w, temp_w, WembT);
    prep_x_kernel<<<(K_EMB * MTOT) / 256, 256, 0, stream>>>(x_enc, x_mark, mean, stdv, xinT);
    wcomb_kernel<<<(2 * D_INNER * K_EMB) / 256, 256, 0, stream>>>(in_proj_w, WembT, Wcomb);
    pepz_kernel<<<PRED_LEN, 256, 0, stream>>>(in_proj_w, PEpZ);
    // PEpT[j][l] = in_proj_xs @ pe^T (analytic B)
    gemm<0, 2, 0><<<dim3(Lseq / 64, D_INNER / 64), 256, 0, stream>>>(
        in_proj_w, nullptr, PEpT, nullptr, D_INNER, Lseq, D_MODEL, D_MODEL, 0);
    // 4a) xs_rawT[j][bl] = Wcomb_xs @ xinT + PEpT[j][l]
    gemm<0, 1, 2><<<dim3(MTOT / 64, D_INNER / 64), 256, 0, stream>>>(
        Wcomb, xinT, xs_rawT, PEpT, D_INNER, MTOT, K_EMB, K_EMB, MTOT);
    // 4b) z96[bt][d] = xinT(tail-remap)^T @ Wcomb_z^T + PEpZ[bt%96][d]
    gemm<2, 0, 3><<<dim3(D_INNER / 64, (Bsz * PRED_LEN) / 64), 256, 0, stream>>>(
        xinT, Wcomb + (size_t)D_INNER * K_EMB, z96, PEpZ,
        Bsz * PRED_LEN, D_INNER, K_EMB, MTOT, K_EMB);
    // 5) depthwise causal conv + SiLU (time-contiguous)
    dwconv_kernel<<<D_INNER * 16, 256, 0, stream>>>(xs_rawT, conv1d_w, conv1d_b, xs_convT);
    // 6) xdblT[p][bl] = x_proj_w @ xs_convT
    gemm<0, 1, 0><<<dim3(MTOT / 64, 1), 256, 0, stream>>>(
        x_proj_w, xs_convT, xdblT, nullptr, 64, MTOT, D_INNER, D_INNER, MTOT);
    // 7) deltaT[d][bl] = softplus(dt_proj_w @ xdblT[:32] + dt_b[d])
    gemm<0, 1, 1><<<dim3(MTOT / 64, D_INNER / 64), 256, 0, stream>>>(
        dt_proj_w, xdblT, deltaT, dt_proj_b, D_INNER, MTOT, DT_RANK, DT_RANK, MTOT);
    // 8) chunked selective scan
    scanA_kernel<<<dim3(Bsz * 16, NCHUNK_A), 256, 0, stream>>>(
        deltaT, xs_convT, xdblT, A_log, Pa, Sa);
    scanB_kernel<<<Bsz * 64, 256, 0, stream>>>(
        deltaT, xs_convT, xdblT, A_log, Dp, Pa, Sa, z96, y96);
    // 9) head + de-normalize
    head_kernel<<<Bsz * PRED_LEN * C_OUT, 64, 0, stream>>>(y96, W, mean, stdv, out);
}